// Round 4
// baseline (644.435 us; speedup 1.0000x reference)
//
#include <hip/hip_runtime.h>
#include <stdint.h>

#define N 8192
#define IN_F 512
#define OUT_F 128
#define NCLS 10
#define ALPHA 0.2f

typedef float f32x4 __attribute__((ext_vector_type(4)));
typedef int   i32x4 __attribute__((ext_vector_type(4)));
typedef short s16x4 __attribute__((ext_vector_type(4)));
typedef short s16x8 __attribute__((ext_vector_type(8)));

__device__ __forceinline__ short f2bf(float x) {
    unsigned u = __builtin_bit_cast(unsigned, x);
    u = (u + 0x7FFFu + ((u >> 16) & 1u)) >> 16;  // RNE
    return (short)u;
}
__device__ __forceinline__ float bf2f(short s) {
    unsigned u = ((unsigned)(unsigned short)s) << 16;
    return __builtin_bit_cast(float, u);
}

// ---------------------------------------------------------------------------
// Kernel 0: split W [512][128] fp32 -> bf16 hi/lo in fragment-blocked layout:
// idx(col,k) = (k>>5)*(128*32) + col*32 + (k&31)
// ---------------------------------------------------------------------------
__global__ void split_w_kernel(const float* __restrict__ W,
                               short* __restrict__ WThi, short* __restrict__ WTlo) {
    int idx = blockIdx.x * 256 + threadIdx.x;       // 512*128 = 65536
    int k = idx >> 7, col = idx & 127;
    float x = W[idx];                               // row-major [k][col]
    short hi = f2bf(x);
    short lo = f2bf(x - bf2f(hi));
    size_t a = (size_t)(k >> 5) * (128 * 32) + (size_t)col * 32 + (k & 31);
    WThi[a] = hi;
    WTlo[a] = lo;
}

// ---------------------------------------------------------------------------
// Kernel 1: Wh = h@W via split-bf16 MFMA (hi*hi + hi*lo + lo*hi, ~fp32 acc).
// Writes Wh1/Wh2 (fp32) and WhT bf16 fragment-blocked [(j>>5)][col][j&31].
// ---------------------------------------------------------------------------
#define WH_ROWS 16
#define WH_STR 520

__global__ __launch_bounds__(256, 2)
void wh_kernel(const float* __restrict__ h, const short* __restrict__ WThi,
               const short* __restrict__ WTlo, const float* __restrict__ a,
               short* __restrict__ WhT, float* __restrict__ Wh1,
               float* __restrict__ Wh2) {
    __shared__ __align__(16) short Ahi[WH_ROWS][WH_STR];
    __shared__ __align__(16) short Alo[WH_ROWS][WH_STR];
    __shared__ __align__(16) float whs[WH_ROWS][OUT_F + 4];

    const int t = threadIdx.x;
    const int r0 = blockIdx.x * WH_ROWS;

    {   // stage h tile [16][512] as bf16 hi/lo
        int row = t >> 4, c4 = t & 15;
        const float* hrow = h + (size_t)(r0 + row) * IN_F;
        #pragma unroll
        for (int jj = 0; jj < 4; ++jj) {
            int k0 = c4 * 8 + jj * 128;
            f32x4 x0 = *(const f32x4*)(hrow + k0);
            f32x4 x1 = *(const f32x4*)(hrow + k0 + 4);
            s16x8 hi, lo;
            #pragma unroll
            for (int e = 0; e < 4; ++e) {
                short h0 = f2bf(x0[e]); hi[e] = h0; lo[e] = f2bf(x0[e] - bf2f(h0));
                short h1 = f2bf(x1[e]); hi[4 + e] = h1; lo[4 + e] = f2bf(x1[e] - bf2f(h1));
            }
            *(s16x8*)&Ahi[row][k0] = hi;
            *(s16x8*)&Alo[row][k0] = lo;
        }
    }
    __syncthreads();

    const int lane = t & 63, w = t >> 6;
    const int q = lane >> 4, ln16 = lane & 15;
    f32x4 acc[2] = {};
    #pragma unroll
    for (int kc = 0; kc < IN_F / 32; ++kc) {
        s16x8 ahi = *(const s16x8*)&Ahi[ln16][kc * 32 + q * 8];
        s16x8 alo = *(const s16x8*)&Alo[ln16][kc * 32 + q * 8];
        #pragma unroll
        for (int nt = 0; nt < 2; ++nt) {
            int col = w * 32 + nt * 16 + ln16;
            size_t boff = (size_t)kc * 4096 + (size_t)col * 32 + q * 8;
            s16x8 bhi = *(const s16x8*)(WThi + boff);
            s16x8 blo = *(const s16x8*)(WTlo + boff);
            acc[nt] = __builtin_amdgcn_mfma_f32_16x16x32_bf16(ahi, bhi, acc[nt], 0, 0, 0);
            acc[nt] = __builtin_amdgcn_mfma_f32_16x16x32_bf16(ahi, blo, acc[nt], 0, 0, 0);
            acc[nt] = __builtin_amdgcn_mfma_f32_16x16x32_bf16(alo, bhi, acc[nt], 0, 0, 0);
        }
    }
    #pragma unroll
    for (int nt = 0; nt < 2; ++nt)
        #pragma unroll
        for (int reg = 0; reg < 4; ++reg)
            whs[q * 4 + reg][w * 32 + nt * 16 + ln16] = acc[nt][reg];
    __syncthreads();

    if (t < 128) {
        int r = t >> 3, s = t & 7;
        float s1 = 0.f, s2 = 0.f;
        #pragma unroll
        for (int cc = 0; cc < 16; ++cc) {
            int c = s * 16 + cc;
            float v = whs[r][c];
            s1 = fmaf(v, a[c], s1);
            s2 = fmaf(v, a[OUT_F + c], s2);
        }
        s1 += __shfl_xor(s1, 1); s1 += __shfl_xor(s1, 2); s1 += __shfl_xor(s1, 4);
        s2 += __shfl_xor(s2, 1); s2 += __shfl_xor(s2, 2); s2 += __shfl_xor(s2, 4);
        if (s == 0) { Wh1[r0 + r] = s1; Wh2[r0 + r] = s2; }
    }

    {   // WhT bf16 fragment-blocked write
        int c = t >> 1, h8 = t & 1;
        s16x8 pack;
        #pragma unroll
        for (int rr = 0; rr < 8; ++rr) pack[rr] = f2bf(whs[h8 * 8 + rr][c]);
        size_t addr = (size_t)(r0 >> 5) * 4096 + (size_t)c * 32 + (r0 & 16) + h8 * 8;
        *(s16x8*)(WhT + addr) = pack;
    }
}

// ---------------------------------------------------------------------------
// Kernel 2: barrier-free fused attention, PHASE-STAGGERED j-loop.
// Each wave owns 16 rows; lanes compute MFMA A-fragments (P) in registers
// (p-phase lane map == A-operand layout). Block it starts at j-phase
// (it & (nit-1)) so concurrent blocks spread dist reads across the whole
// address range (HBM channel decorrelation). Next-iter dist/Wh2 batches are
// explicitly double-buffered in registers — no barrier, so the p-phase wait
// only covers the previous batch and overlaps the MFMA phase.
// Block = 4 waves = 64 rows; grid = 128 i-tiles x SPLIT j-groups.
// ---------------------------------------------------------------------------
#define BK 128

__global__ __launch_bounds__(256, 4)
void attn_kernel(const int* __restrict__ dist, const short* __restrict__ WhT,
                 const float* __restrict__ Wh1v, const float* __restrict__ Wh2v,
                 float* __restrict__ acc_part, float* __restrict__ l_part,
                 int nit) {
    const int t = threadIdx.x;
    const int it = blockIdx.x & 127;        // 128 i-tiles of 64 rows
    const int sp = blockIdx.x >> 7;
    const int i0 = it * 64;
    const int lane = t & 63, w = t >> 6;
    const int q = lane >> 4, m = lane & 15;
    const int row = i0 + w * 16 + m;
    const int j0 = sp * nit * BK;
    const int phase = it & (nit - 1);       // nit is a power of two

    const int* __restrict__ drow = dist + (size_t)row * N + j0;
    const float* __restrict__ wh2p = Wh2v + j0;
    const float wh1 = Wh1v[row];
    float l_acc = 0.f;
    f32x4 acc[8] = {};   // 16 rows x 128 cols per wave (8 n-tiles)

    // prologue: load batch for first (staggered) tile
    i32x4 d[8];
    f32x4 w2[2][2];
    {
        const int jb = phase * BK;
        #pragma unroll
        for (int kc = 0; kc < 4; ++kc) {
            d[kc * 2]     = *(const i32x4*)(drow + jb + kc * 32 + q * 8);
            d[kc * 2 + 1] = *(const i32x4*)(drow + jb + kc * 32 + q * 8 + 4);
        }
        // Wh2 slice for this lane's k-positions: two halves per 32-chunk? we
        // need w2 at (jb + kc*32 + q*8 .. +7) for kc=0..3 -> 4 pairs; keep 2
        // pairs per register set of 2 (recomputed per kc below for kc>=2)
        w2[0][0] = *(const f32x4*)(wh2p + jb + 0 * 32 + q * 8);
        w2[0][1] = *(const f32x4*)(wh2p + jb + 0 * 32 + q * 8 + 4);
        w2[1][0] = *(const f32x4*)(wh2p + jb + 1 * 32 + q * 8);
        w2[1][1] = *(const f32x4*)(wh2p + jb + 1 * 32 + q * 8 + 4);
    }

    for (int kt = 0; kt < nit; ++kt) {
        const int cur = (kt + phase) & (nit - 1);
        const int jb = cur * BK;
        const bool more = (kt + 1) < nit;
        const int jbn = (((kt + 1 + phase) & (nit - 1))) * BK;

        // issue next-iter batch first (overlaps with this iter's compute)
        i32x4 dn[8];
        f32x4 w2n[2][2];
        if (more) {
            #pragma unroll
            for (int kc = 0; kc < 4; ++kc) {
                dn[kc * 2]     = *(const i32x4*)(drow + jbn + kc * 32 + q * 8);
                dn[kc * 2 + 1] = *(const i32x4*)(drow + jbn + kc * 32 + q * 8 + 4);
            }
            w2n[0][0] = *(const f32x4*)(wh2p + jbn + 0 * 32 + q * 8);
            w2n[0][1] = *(const f32x4*)(wh2p + jbn + 0 * 32 + q * 8 + 4);
            w2n[1][0] = *(const f32x4*)(wh2p + jbn + 1 * 32 + q * 8);
            w2n[1][1] = *(const f32x4*)(wh2p + jbn + 1 * 32 + q * 8 + 4);
        }

        // p-phase: A-fragments in registers (kc=0,1 from w2 regs; 2,3 loaded
        // here — they were issued last iter as part of the same batch window)
        s16x8 afr[4];
        #pragma unroll
        for (int kc = 0; kc < 4; ++kc) {
            f32x4 w20, w21;
            if (kc < 2) { w20 = w2[kc][0]; w21 = w2[kc][1]; }
            else {
                w20 = *(const f32x4*)(wh2p + jb + kc * 32 + q * 8);
                w21 = *(const f32x4*)(wh2p + jb + kc * 32 + q * 8 + 4);
            }
            #pragma unroll
            for (int e = 0; e < 4; ++e) {
                float sv = wh1 + w20[e];
                float lr = fmaxf(sv, ALPHA * sv);
                float pv = (d[kc * 2][e] > 0) ? __expf(lr) : 0.f;
                l_acc += pv;
                unsigned u = __builtin_bit_cast(unsigned, pv);
                afr[kc][e] = (short)((u + 0x8000u) >> 16);
                float sv1 = wh1 + w21[e];
                float lr1 = fmaxf(sv1, ALPHA * sv1);
                float pv1 = (d[kc * 2 + 1][e] > 0) ? __expf(lr1) : 0.f;
                l_acc += pv1;
                unsigned u1 = __builtin_bit_cast(unsigned, pv1);
                afr[kc][4 + e] = (short)((u1 + 0x8000u) >> 16);
            }
        }
        // MFMA phase: B fragments from L1/L2 (blocked layout)
        const short* bb = WhT + (size_t)((j0 + jb) >> 5) * 4096 + q * 8;
        #pragma unroll
        for (int kc = 0; kc < 4; ++kc) {
            const short* bkc = bb + (size_t)kc * 4096;
            #pragma unroll
            for (int nt = 0; nt < 8; ++nt) {
                s16x8 bfr = *(const s16x8*)(bkc + (nt * 16 + m) * 32);
                acc[nt] = __builtin_amdgcn_mfma_f32_16x16x32_bf16(afr[kc], bfr, acc[nt], 0, 0, 0);
            }
        }
        if (more) {
            #pragma unroll
            for (int u = 0; u < 8; ++u) d[u] = dn[u];
            #pragma unroll
            for (int u = 0; u < 2; ++u) { w2[u][0] = w2n[u][0]; w2[u][1] = w2n[u][1]; }
        }
    }

    // row-sum over the 4 q-slices
    l_acc += __shfl_xor(l_acc, 16);
    l_acc += __shfl_xor(l_acc, 32);
    if (q == 0) l_part[(size_t)sp * N + row] = l_acc;

    // partials: out row = i0 + w*16 + q*4 + reg, col = nt*16 + m
    float* ap = acc_part + (size_t)sp * N * OUT_F
              + ((size_t)i0 + w * 16 + q * 4) * OUT_F + m;
    #pragma unroll
    for (int reg = 0; reg < 4; ++reg)
        #pragma unroll
        for (int nt = 0; nt < 8; ++nt)
            ap[(size_t)reg * OUT_F + nt * 16] = acc[nt][reg];
}

// ---------------------------------------------------------------------------
// Kernel 3: reduce partials, softmax-divide, elu, classifier.
// ---------------------------------------------------------------------------
__global__ __launch_bounds__(256, 4)
void reduce_kernel(const float* __restrict__ acc_part, const float* __restrict__ l_part,
                   const float* __restrict__ Wc, const float* __restrict__ bcv,
                   float* __restrict__ out, int split) {
    __shared__ __align__(16) float hu[16][OUT_F + 4];
    const int t = threadIdx.x;
    const int i0 = blockIdx.x * 16;
    const int row = t >> 4, cg = t & 15;

    f32x4 v0 = {0.f, 0.f, 0.f, 0.f}, v1 = {0.f, 0.f, 0.f, 0.f};
    float l = 0.f;
    for (int s = 0; s < split; ++s) {
        const float* ap = acc_part + (size_t)s * N * OUT_F + (size_t)(i0 + row) * OUT_F + cg * 8;
        v0 += *(const f32x4*)ap;
        v1 += *(const f32x4*)(ap + 4);
        l += l_part[(size_t)s * N + i0 + row];
    }
    float inv = 1.f / l;
    #pragma unroll
    for (int e = 0; e < 4; ++e) {
        float x0 = v0[e] * inv; x0 = x0 > 0.f ? x0 : (__expf(x0) - 1.f);
        float x1 = v1[e] * inv; x1 = x1 > 0.f ? x1 : (__expf(x1) - 1.f);
        hu[row][cg * 8 + e] = x0;
        hu[row][cg * 8 + 4 + e] = x1;
    }
    __syncthreads();

    if (t < 16 * NCLS) {
        int rr = t / NCLS, cls = t - rr * NCLS;
        const f32x4* hurow = (const f32x4*)&hu[rr][0];
        const f32x4* wcrow = (const f32x4*)(Wc + cls * OUT_F);
        float sum = bcv[cls];
        #pragma unroll 8
        for (int c4 = 0; c4 < OUT_F / 4; ++c4) {
            f32x4 hv = hurow[c4];
            f32x4 wv = wcrow[c4];
            sum += hv[0] * wv[0] + hv[1] * wv[1] + hv[2] * wv[2] + hv[3] * wv[3];
        }
        out[(size_t)(i0 + rr) * NCLS + cls] = sum;
    }
}

// ---------------------------------------------------------------------------
extern "C" void kernel_launch(void* const* d_in, const int* in_sizes, int n_in,
                              void* d_out, int out_size, void* d_ws, size_t ws_size,
                              hipStream_t stream) {
    const float* h    = (const float*)d_in[0];
    const int*   dist = (const int*)d_in[1];
    const float* W    = (const float*)d_in[2];
    const float* a    = (const float*)d_in[3];
    const float* Wc   = (const float*)d_in[4];
    const float* bc   = (const float*)d_in[5];
    float* out = (float*)d_out;

    char* ws = (char*)d_ws;
    size_t off = 0;
    short* WhT  = (short*)(ws + off); off += (size_t)OUT_F * N * 2;     // 2 MB
    short* WThi = (short*)(ws + off); off += (size_t)IN_F * OUT_F * 2;  // 128 KB
    short* WTlo = (short*)(ws + off); off += (size_t)IN_F * OUT_F * 2;  // 128 KB
    float* Wh1  = (float*)(ws + off); off += (size_t)N * 4;
    float* Wh2  = (float*)(ws + off); off += (size_t)N * 4;

    size_t per_split = (size_t)N * OUT_F * 4 + (size_t)N * 4;
    int split = 8;
    while (split > 1 && off + (size_t)split * per_split > ws_size) split >>= 1;
    float* acc_part = (float*)(ws + off); off += (size_t)split * N * OUT_F * 4;
    float* l_part   = (float*)(ws + off);

    hipLaunchKernelGGL(split_w_kernel, dim3(256), dim3(256), 0, stream, W, WThi, WTlo);
    hipLaunchKernelGGL(wh_kernel, dim3(N / WH_ROWS), dim3(256), 0, stream,
                       h, WThi, WTlo, a, WhT, Wh1, Wh2);
    int nit = N / (BK * split);
    hipLaunchKernelGGL(attn_kernel, dim3(128 * split), dim3(256), 0, stream,
                       dist, WhT, Wh1, Wh2, acc_part, l_part, nit);
    hipLaunchKernelGGL(reduce_kernel, dim3(N / 16), dim3(256), 0, stream,
                       acc_part, l_part, Wc, bc, out, split);
}

// Round 5
// 475.246 us; speedup vs baseline: 1.3560x; 1.3560x over previous
//
#include <hip/hip_runtime.h>
#include <stdint.h>

#define N 8192
#define IN_F 512
#define OUT_F 128
#define NCLS 10
#define ALPHA 0.2f

typedef float f32x4 __attribute__((ext_vector_type(4)));
typedef int   i32x4 __attribute__((ext_vector_type(4)));
typedef short s16x4 __attribute__((ext_vector_type(4)));
typedef short s16x8 __attribute__((ext_vector_type(8)));

__device__ __forceinline__ short f2bf(float x) {
    unsigned u = __builtin_bit_cast(unsigned, x);
    u = (u + 0x7FFFu + ((u >> 16) & 1u)) >> 16;  // RNE
    return (short)u;
}
__device__ __forceinline__ float bf2f(short s) {
    unsigned u = ((unsigned)(unsigned short)s) << 16;
    return __builtin_bit_cast(float, u);
}

// ---------------------------------------------------------------------------
// Kernel 0: split W [512][128] fp32 -> bf16 hi/lo in fragment-blocked layout:
// idx(col,k) = (k>>5)*(128*32) + col*32 + (k&31)
// ---------------------------------------------------------------------------
__global__ void split_w_kernel(const float* __restrict__ W,
                               short* __restrict__ WThi, short* __restrict__ WTlo) {
    int idx = blockIdx.x * 256 + threadIdx.x;       // 512*128 = 65536
    int k = idx >> 7, col = idx & 127;
    float x = W[idx];                               // row-major [k][col]
    short hi = f2bf(x);
    short lo = f2bf(x - bf2f(hi));
    size_t a = (size_t)(k >> 5) * (128 * 32) + (size_t)col * 32 + (k & 31);
    WThi[a] = hi;
    WTlo[a] = lo;
}

// ---------------------------------------------------------------------------
// Kernel 1: Wh = h@W via split-bf16 MFMA (hi*hi + hi*lo + lo*hi, ~fp32 acc).
// Writes Wh1/Wh2 (fp32) and WhT bf16 fragment-blocked [(j>>5)][col][j&31].
// ---------------------------------------------------------------------------
#define WH_ROWS 16
#define WH_STR 520

__global__ __launch_bounds__(256, 2)
void wh_kernel(const float* __restrict__ h, const short* __restrict__ WThi,
               const short* __restrict__ WTlo, const float* __restrict__ a,
               short* __restrict__ WhT, float* __restrict__ Wh1,
               float* __restrict__ Wh2) {
    __shared__ __align__(16) short Ahi[WH_ROWS][WH_STR];
    __shared__ __align__(16) short Alo[WH_ROWS][WH_STR];
    __shared__ __align__(16) float whs[WH_ROWS][OUT_F + 4];

    const int t = threadIdx.x;
    const int r0 = blockIdx.x * WH_ROWS;

    {   // stage h tile [16][512] as bf16 hi/lo
        int row = t >> 4, c4 = t & 15;
        const float* hrow = h + (size_t)(r0 + row) * IN_F;
        #pragma unroll
        for (int jj = 0; jj < 4; ++jj) {
            int k0 = c4 * 8 + jj * 128;
            f32x4 x0 = *(const f32x4*)(hrow + k0);
            f32x4 x1 = *(const f32x4*)(hrow + k0 + 4);
            s16x8 hi, lo;
            #pragma unroll
            for (int e = 0; e < 4; ++e) {
                short h0 = f2bf(x0[e]); hi[e] = h0; lo[e] = f2bf(x0[e] - bf2f(h0));
                short h1 = f2bf(x1[e]); hi[4 + e] = h1; lo[4 + e] = f2bf(x1[e] - bf2f(h1));
            }
            *(s16x8*)&Ahi[row][k0] = hi;
            *(s16x8*)&Alo[row][k0] = lo;
        }
    }
    __syncthreads();

    const int lane = t & 63, w = t >> 6;
    const int q = lane >> 4, ln16 = lane & 15;
    f32x4 acc[2] = {};
    #pragma unroll
    for (int kc = 0; kc < IN_F / 32; ++kc) {
        s16x8 ahi = *(const s16x8*)&Ahi[ln16][kc * 32 + q * 8];
        s16x8 alo = *(const s16x8*)&Alo[ln16][kc * 32 + q * 8];
        #pragma unroll
        for (int nt = 0; nt < 2; ++nt) {
            int col = w * 32 + nt * 16 + ln16;
            size_t boff = (size_t)kc * 4096 + (size_t)col * 32 + q * 8;
            s16x8 bhi = *(const s16x8*)(WThi + boff);
            s16x8 blo = *(const s16x8*)(WTlo + boff);
            acc[nt] = __builtin_amdgcn_mfma_f32_16x16x32_bf16(ahi, bhi, acc[nt], 0, 0, 0);
            acc[nt] = __builtin_amdgcn_mfma_f32_16x16x32_bf16(ahi, blo, acc[nt], 0, 0, 0);
            acc[nt] = __builtin_amdgcn_mfma_f32_16x16x32_bf16(alo, bhi, acc[nt], 0, 0, 0);
        }
    }
    #pragma unroll
    for (int nt = 0; nt < 2; ++nt)
        #pragma unroll
        for (int reg = 0; reg < 4; ++reg)
            whs[q * 4 + reg][w * 32 + nt * 16 + ln16] = acc[nt][reg];
    __syncthreads();

    if (t < 128) {
        int r = t >> 3, s = t & 7;
        float s1 = 0.f, s2 = 0.f;
        #pragma unroll
        for (int cc = 0; cc < 16; ++cc) {
            int c = s * 16 + cc;
            float v = whs[r][c];
            s1 = fmaf(v, a[c], s1);
            s2 = fmaf(v, a[OUT_F + c], s2);
        }
        s1 += __shfl_xor(s1, 1); s1 += __shfl_xor(s1, 2); s1 += __shfl_xor(s1, 4);
        s2 += __shfl_xor(s2, 1); s2 += __shfl_xor(s2, 2); s2 += __shfl_xor(s2, 4);
        if (s == 0) { Wh1[r0 + r] = s1; Wh2[r0 + r] = s2; }
    }

    {   // WhT bf16 fragment-blocked write
        int c = t >> 1, h8 = t & 1;
        s16x8 pack;
        #pragma unroll
        for (int rr = 0; rr < 8; ++rr) pack[rr] = f2bf(whs[h8 * 8 + rr][c]);
        size_t addr = (size_t)(r0 >> 5) * 4096 + (size_t)c * 32 + (r0 & 16) + h8 * 8;
        *(s16x8*)(WhT + addr) = pack;
    }
}

// ---------------------------------------------------------------------------
// Kernel 2: barrier-free fused attention, phase-staggered j-loop, batched
// dist loads. Each wave owns 16 rows; lanes compute MFMA A-fragments (P) in
// registers (p-phase lane map == A-operand layout). Block it starts at
// j-phase (it & (nit-1)) so concurrent blocks spread dist reads across the
// whole 256 MB (HBM-channel / L3-slice decorrelation — R4 measured 2.6 TB/s
// delivery with stagger vs 0.87 without). The 8 dist loads are issued as ONE
// batch per iteration and fenced with sched_barrier(0) so the compiler
// cannot re-sink them to their uses (R3's VGPR=52 showed exactly that,
// causing 4 serialized HBM round-trips/iter). NO explicit double-buffer:
// R4 proved it spills (+730 MB scratch traffic).
// Block = 4 waves = 64 rows; grid = 128 i-tiles x SPLIT j-groups.
// ---------------------------------------------------------------------------
#define BK 128

__global__ __launch_bounds__(256, 4)
void attn_kernel(const int* __restrict__ dist, const short* __restrict__ WhT,
                 const float* __restrict__ Wh1v, const float* __restrict__ Wh2v,
                 float* __restrict__ acc_part, float* __restrict__ l_part,
                 int nit) {
    const int t = threadIdx.x;
    const int it = blockIdx.x & 127;        // 128 i-tiles of 64 rows
    const int sp = blockIdx.x >> 7;
    const int i0 = it * 64;
    const int lane = t & 63, w = t >> 6;
    const int q = lane >> 4, m = lane & 15;
    const int row = i0 + w * 16 + m;
    const int j0 = sp * nit * BK;
    const int phase = it & (nit - 1);       // nit is a power of two

    const int* __restrict__ drow = dist + (size_t)row * N + j0;
    const float* __restrict__ wh2p = Wh2v + j0;
    const float wh1 = Wh1v[row];
    float l_acc = 0.f;
    f32x4 acc[8] = {};   // 16 rows x 128 cols per wave (8 n-tiles)

    for (int kt = 0; kt < nit; ++kt) {
        const int jb = ((kt + phase) & (nit - 1)) * BK;

        // batched dist loads: 8x dwordx4 issued together, then fenced
        i32x4 d[8];
        #pragma unroll
        for (int kc = 0; kc < 4; ++kc) {
            d[kc * 2]     = *(const i32x4*)(drow + jb + kc * 32 + q * 8);
            d[kc * 2 + 1] = *(const i32x4*)(drow + jb + kc * 32 + q * 8 + 4);
        }
        __builtin_amdgcn_sched_barrier(0);  // keep the batch issued up front

        // p-phase: A-fragments in registers; wh2 is 32 KB and L1/L2-hot,
        // loaded inline
        s16x8 afr[4];
        #pragma unroll
        for (int kc = 0; kc < 4; ++kc) {
            f32x4 w20 = *(const f32x4*)(wh2p + jb + kc * 32 + q * 8);
            f32x4 w21 = *(const f32x4*)(wh2p + jb + kc * 32 + q * 8 + 4);
            #pragma unroll
            for (int e = 0; e < 4; ++e) {
                float sv = wh1 + w20[e];
                float lr = fmaxf(sv, ALPHA * sv);
                float pv = (d[kc * 2][e] > 0) ? __expf(lr) : 0.f;
                l_acc += pv;
                unsigned u = __builtin_bit_cast(unsigned, pv);
                afr[kc][e] = (short)((u + 0x8000u) >> 16);          // bf16
                float sv1 = wh1 + w21[e];
                float lr1 = fmaxf(sv1, ALPHA * sv1);
                float pv1 = (d[kc * 2 + 1][e] > 0) ? __expf(lr1) : 0.f;
                l_acc += pv1;
                unsigned u1 = __builtin_bit_cast(unsigned, pv1);
                afr[kc][4 + e] = (short)((u1 + 0x8000u) >> 16);
            }
        }
        // MFMA phase: B fragments from L1/L2 (blocked layout)
        const short* bb = WhT + (size_t)((j0 + jb) >> 5) * 4096 + q * 8;
        #pragma unroll
        for (int kc = 0; kc < 4; ++kc) {
            const short* bkc = bb + (size_t)kc * 4096;
            #pragma unroll
            for (int nt = 0; nt < 8; ++nt) {
                s16x8 bfr = *(const s16x8*)(bkc + (nt * 16 + m) * 32);
                acc[nt] = __builtin_amdgcn_mfma_f32_16x16x32_bf16(afr[kc], bfr, acc[nt], 0, 0, 0);
            }
        }
    }

    // row-sum over the 4 q-slices
    l_acc += __shfl_xor(l_acc, 16);
    l_acc += __shfl_xor(l_acc, 32);
    if (q == 0) l_part[(size_t)sp * N + row] = l_acc;

    // partials: out row = i0 + w*16 + q*4 + reg, col = nt*16 + m
    float* ap = acc_part + (size_t)sp * N * OUT_F
              + ((size_t)i0 + w * 16 + q * 4) * OUT_F + m;
    #pragma unroll
    for (int reg = 0; reg < 4; ++reg)
        #pragma unroll
        for (int nt = 0; nt < 8; ++nt)
            ap[(size_t)reg * OUT_F + nt * 16] = acc[nt][reg];
}

// ---------------------------------------------------------------------------
// Kernel 3: reduce partials, softmax-divide, elu, classifier.
// ---------------------------------------------------------------------------
__global__ __launch_bounds__(256, 4)
void reduce_kernel(const float* __restrict__ acc_part, const float* __restrict__ l_part,
                   const float* __restrict__ Wc, const float* __restrict__ bcv,
                   float* __restrict__ out, int split) {
    __shared__ __align__(16) float hu[16][OUT_F + 4];
    const int t = threadIdx.x;
    const int i0 = blockIdx.x * 16;
    const int row = t >> 4, cg = t & 15;

    f32x4 v0 = {0.f, 0.f, 0.f, 0.f}, v1 = {0.f, 0.f, 0.f, 0.f};
    float l = 0.f;
    for (int s = 0; s < split; ++s) {
        const float* ap = acc_part + (size_t)s * N * OUT_F + (size_t)(i0 + row) * OUT_F + cg * 8;
        v0 += *(const f32x4*)ap;
        v1 += *(const f32x4*)(ap + 4);
        l += l_part[(size_t)s * N + i0 + row];
    }
    float inv = 1.f / l;
    #pragma unroll
    for (int e = 0; e < 4; ++e) {
        float x0 = v0[e] * inv; x0 = x0 > 0.f ? x0 : (__expf(x0) - 1.f);
        float x1 = v1[e] * inv; x1 = x1 > 0.f ? x1 : (__expf(x1) - 1.f);
        hu[row][cg * 8 + e] = x0;
        hu[row][cg * 8 + 4 + e] = x1;
    }
    __syncthreads();

    if (t < 16 * NCLS) {
        int rr = t / NCLS, cls = t - rr * NCLS;
        const f32x4* hurow = (const f32x4*)&hu[rr][0];
        const f32x4* wcrow = (const f32x4*)(Wc + cls * OUT_F);
        float sum = bcv[cls];
        #pragma unroll 8
        for (int c4 = 0; c4 < OUT_F / 4; ++c4) {
            f32x4 hv = hurow[c4];
            f32x4 wv = wcrow[c4];
            sum += hv[0] * wv[0] + hv[1] * wv[1] + hv[2] * wv[2] + hv[3] * wv[3];
        }
        out[(size_t)(i0 + rr) * NCLS + cls] = sum;
    }
}

// ---------------------------------------------------------------------------
extern "C" void kernel_launch(void* const* d_in, const int* in_sizes, int n_in,
                              void* d_out, int out_size, void* d_ws, size_t ws_size,
                              hipStream_t stream) {
    const float* h    = (const float*)d_in[0];
    const int*   dist = (const int*)d_in[1];
    const float* W    = (const float*)d_in[2];
    const float* a    = (const float*)d_in[3];
    const float* Wc   = (const float*)d_in[4];
    const float* bc   = (const float*)d_in[5];
    float* out = (float*)d_out;

    char* ws = (char*)d_ws;
    size_t off = 0;
    short* WhT  = (short*)(ws + off); off += (size_t)OUT_F * N * 2;     // 2 MB
    short* WThi = (short*)(ws + off); off += (size_t)IN_F * OUT_F * 2;  // 128 KB
    short* WTlo = (short*)(ws + off); off += (size_t)IN_F * OUT_F * 2;  // 128 KB
    float* Wh1  = (float*)(ws + off); off += (size_t)N * 4;
    float* Wh2  = (float*)(ws + off); off += (size_t)N * 4;

    size_t per_split = (size_t)N * OUT_F * 4 + (size_t)N * 4;
    int split = 8;
    while (split > 1 && off + (size_t)split * per_split > ws_size) split >>= 1;
    float* acc_part = (float*)(ws + off); off += (size_t)split * N * OUT_F * 4;
    float* l_part   = (float*)(ws + off);

    hipLaunchKernelGGL(split_w_kernel, dim3(256), dim3(256), 0, stream, W, WThi, WTlo);
    hipLaunchKernelGGL(wh_kernel, dim3(N / WH_ROWS), dim3(256), 0, stream,
                       h, WThi, WTlo, a, WhT, Wh1, Wh2);
    int nit = N / (BK * split);
    hipLaunchKernelGGL(attn_kernel, dim3(128 * split), dim3(256), 0, stream,
                       dist, WhT, Wh1, Wh2, acc_part, l_part, nit);
    hipLaunchKernelGGL(reduce_kernel, dim3(N / 16), dim3(256), 0, stream,
                       acc_part, l_part, Wc, bc, out, split);
}

// Round 6
// 465.239 us; speedup vs baseline: 1.3852x; 1.0215x over previous
//
#include <hip/hip_runtime.h>
#include <stdint.h>

#define N 8192
#define IN_F 512
#define OUT_F 128
#define NCLS 10
#define ALPHA 0.2f

#define WCOLS 1024          // j-window per split group
#define NSP (N / WCOLS)     // 8 split groups
#define BK 128              // j per inner iteration
#define NIT (WCOLS / BK)    // 8 iterations
#define MSTR 33             // LDS mask row stride in u32 (32 + 1 pad -> conflict-free)

typedef float f32x4 __attribute__((ext_vector_type(4)));
typedef int   i32x4 __attribute__((ext_vector_type(4)));
typedef short s16x8 __attribute__((ext_vector_type(8)));

__device__ __forceinline__ short f2bf(float x) {
    unsigned u = __builtin_bit_cast(unsigned, x);
    u = (u + 0x7FFFu + ((u >> 16) & 1u)) >> 16;  // RNE
    return (short)u;
}
__device__ __forceinline__ float bf2f(short s) {
    unsigned u = ((unsigned)(unsigned short)s) << 16;
    return __builtin_bit_cast(float, u);
}

// ---------------------------------------------------------------------------
// Kernel 0: split W [512][128] fp32 -> bf16 hi/lo, fragment-blocked:
// idx(col,k) = (k>>5)*(128*32) + col*32 + (k&31)
// ---------------------------------------------------------------------------
__global__ void split_w_kernel(const float* __restrict__ W,
                               short* __restrict__ WThi, short* __restrict__ WTlo) {
    int idx = blockIdx.x * 256 + threadIdx.x;       // 512*128 = 65536
    int k = idx >> 7, col = idx & 127;
    float x = W[idx];
    short hi = f2bf(x);
    short lo = f2bf(x - bf2f(hi));
    size_t a = (size_t)(k >> 5) * (128 * 32) + (size_t)col * 32 + (k & 31);
    WThi[a] = hi;
    WTlo[a] = lo;
}

// ---------------------------------------------------------------------------
// Kernel 1: Wh = h@W via split-bf16 MFMA (~fp32 accuracy). Writes Wh1/Wh2
// (fp32) and WhT bf16 fragment-blocked [(j>>5)][col][j&31].
// ---------------------------------------------------------------------------
#define WH_ROWS 16
#define WH_STR 520

__global__ __launch_bounds__(256, 2)
void wh_kernel(const float* __restrict__ h, const short* __restrict__ WThi,
               const short* __restrict__ WTlo, const float* __restrict__ a,
               short* __restrict__ WhT, float* __restrict__ Wh1,
               float* __restrict__ Wh2) {
    __shared__ __align__(16) short Ahi[WH_ROWS][WH_STR];
    __shared__ __align__(16) short Alo[WH_ROWS][WH_STR];
    __shared__ __align__(16) float whs[WH_ROWS][OUT_F + 4];

    const int t = threadIdx.x;
    const int r0 = blockIdx.x * WH_ROWS;

    {   // stage h tile [16][512] as bf16 hi/lo
        int row = t >> 4, c4 = t & 15;
        const float* hrow = h + (size_t)(r0 + row) * IN_F;
        #pragma unroll
        for (int jj = 0; jj < 4; ++jj) {
            int k0 = c4 * 8 + jj * 128;
            f32x4 x0 = *(const f32x4*)(hrow + k0);
            f32x4 x1 = *(const f32x4*)(hrow + k0 + 4);
            s16x8 hi, lo;
            #pragma unroll
            for (int e = 0; e < 4; ++e) {
                short h0 = f2bf(x0[e]); hi[e] = h0; lo[e] = f2bf(x0[e] - bf2f(h0));
                short h1 = f2bf(x1[e]); hi[4 + e] = h1; lo[4 + e] = f2bf(x1[e] - bf2f(h1));
            }
            *(s16x8*)&Ahi[row][k0] = hi;
            *(s16x8*)&Alo[row][k0] = lo;
        }
    }
    __syncthreads();

    const int lane = t & 63, w = t >> 6;
    const int q = lane >> 4, ln16 = lane & 15;
    f32x4 acc[2] = {};
    #pragma unroll
    for (int kc = 0; kc < IN_F / 32; ++kc) {
        s16x8 ahi = *(const s16x8*)&Ahi[ln16][kc * 32 + q * 8];
        s16x8 alo = *(const s16x8*)&Alo[ln16][kc * 32 + q * 8];
        #pragma unroll
        for (int nt = 0; nt < 2; ++nt) {
            int col = w * 32 + nt * 16 + ln16;
            size_t boff = (size_t)kc * 4096 + (size_t)col * 32 + q * 8;
            s16x8 bhi = *(const s16x8*)(WThi + boff);
            s16x8 blo = *(const s16x8*)(WTlo + boff);
            acc[nt] = __builtin_amdgcn_mfma_f32_16x16x32_bf16(ahi, bhi, acc[nt], 0, 0, 0);
            acc[nt] = __builtin_amdgcn_mfma_f32_16x16x32_bf16(ahi, blo, acc[nt], 0, 0, 0);
            acc[nt] = __builtin_amdgcn_mfma_f32_16x16x32_bf16(alo, bhi, acc[nt], 0, 0, 0);
        }
    }
    #pragma unroll
    for (int nt = 0; nt < 2; ++nt)
        #pragma unroll
        for (int reg = 0; reg < 4; ++reg)
            whs[q * 4 + reg][w * 32 + nt * 16 + ln16] = acc[nt][reg];
    __syncthreads();

    if (t < 128) {
        int r = t >> 3, s = t & 7;
        float s1 = 0.f, s2 = 0.f;
        #pragma unroll
        for (int cc = 0; cc < 16; ++cc) {
            int c = s * 16 + cc;
            float v = whs[r][c];
            s1 = fmaf(v, a[c], s1);
            s2 = fmaf(v, a[OUT_F + c], s2);
        }
        s1 += __shfl_xor(s1, 1); s1 += __shfl_xor(s1, 2); s1 += __shfl_xor(s1, 4);
        s2 += __shfl_xor(s2, 1); s2 += __shfl_xor(s2, 2); s2 += __shfl_xor(s2, 4);
        if (s == 0) { Wh1[r0 + r] = s1; Wh2[r0 + r] = s2; }
    }

    {   // WhT bf16 fragment-blocked write
        int c = t >> 1, h8 = t & 1;
        s16x8 pack;
        #pragma unroll
        for (int rr = 0; rr < 8; ++rr) pack[rr] = f2bf(whs[h8 * 8 + rr][c]);
        size_t addr = (size_t)(r0 >> 5) * 4096 + (size_t)c * 32 + (r0 & 16) + h8 * 8;
        *(s16x8*)(WhT + addr) = pack;
    }
}

// ---------------------------------------------------------------------------
// Kernel 2: two-phase fused attention.
// Phase 1 — STREAM: each wave reads dist one ROW-SEGMENT at a time: 64 lanes
//   x 16 B = 1 KB fully contiguous per instruction (the 6.7 TB/s pattern),
//   packs dist>0 into a 1-bit/elem LDS mask via 3 shfl_xor folds. No
//   dependent long-latency chains; dist read exactly once.
// Phase 2 — CONSUME: R5's register-fragment flash loop, but mask + Wh2 come
//   from LDS and WhT B-fragments from L2: zero HBM in the latency-sensitive
//   loop. Lane map of p-phase == MFMA A-operand layout (m=lane&15,
//   k=(lane>>4)*8+j). acc stays in AGPRs; partials to workspace.
// Block = 4 waves = 64 rows x 1024-col window; grid = 128 i-tiles x 8 sp.
// ---------------------------------------------------------------------------
__global__ __launch_bounds__(256, 4)
void attn_kernel(const int* __restrict__ dist, const short* __restrict__ WhT,
                 const float* __restrict__ Wh1v, const float* __restrict__ Wh2v,
                 float* __restrict__ acc_part, float* __restrict__ l_part) {
    __shared__ unsigned maskL[64 * MSTR];            // 64 rows x 1024 bits
    __shared__ __align__(16) float wh2L[WCOLS];

    const int t = threadIdx.x;
    const int it = blockIdx.x & 127;
    const int sp = blockIdx.x >> 7;
    const int i0 = it * 64;
    const int j0 = sp * WCOLS;
    const int lane = t & 63, w = t >> 6;
    const int q = lane >> 4, m = lane & 15;

    // ---- phase 1: dist slice (64 rows x 1024 ints) -> LDS bitmask
    {
        const int l = lane;
        #pragma unroll 4
        for (int rr = 0; rr < 16; ++rr) {
            const int r = w * 16 + rr;
            const int* rp = dist + (size_t)(i0 + r) * N + j0 + l * 4;
            #pragma unroll
            for (int p = 0; p < 4; ++p) {
                i32x4 v = *(const i32x4*)(rp + p * 256);   // 1 KB/instr contiguous
                unsigned nib = (unsigned)(v[0] > 0) | ((unsigned)(v[1] > 0) << 1)
                             | ((unsigned)(v[2] > 0) << 2) | ((unsigned)(v[3] > 0) << 3);
                unsigned b = nib | (__shfl_xor(nib, 1) << 4);   // even lanes: byte
                b = b | (__shfl_xor(b, 2) << 8);                // l%4==0: u16
                b = b | (__shfl_xor(b, 4) << 16);               // l%8==0: u32
                if ((l & 7) == 0) maskL[r * MSTR + p * 8 + (l >> 3)] = b;
            }
        }
        if (t < WCOLS / 4)   // stage Wh2 window (4 KB)
            *(f32x4*)&wh2L[t * 4] = *(const f32x4*)(Wh2v + j0 + t * 4);
    }
    __syncthreads();

    // ---- phase 2: flash loop from LDS/L2
    const int row = i0 + w * 16 + m;
    const float wh1 = Wh1v[row];
    float l_acc = 0.f;
    f32x4 acc[8] = {};   // 16 rows x 128 cols per wave
    const unsigned* mrow = &maskL[(w * 16 + m) * MSTR];

    for (int kt = 0; kt < NIT; ++kt) {
        const int jb = kt * BK;
        s16x8 afr[4];
        #pragma unroll
        for (int kc = 0; kc < 4; ++kc) {
            unsigned mw = mrow[(jb >> 5) + kc];       // conflict-free (stride 33)
            unsigned byq = (mw >> (q * 8)) & 255u;    // this lane's 8 j-bits
            f32x4 w20 = *(const f32x4*)&wh2L[jb + kc * 32 + q * 8];
            f32x4 w21 = *(const f32x4*)&wh2L[jb + kc * 32 + q * 8 + 4];
            #pragma unroll
            for (int e = 0; e < 4; ++e) {
                float sv = wh1 + w20[e];
                float lr = fmaxf(sv, ALPHA * sv);
                float pv = ((byq >> e) & 1u) ? __expf(lr) : 0.f;
                l_acc += pv;
                afr[kc][e] = (short)((__builtin_bit_cast(unsigned, pv) + 0x8000u) >> 16);
                float sv1 = wh1 + w21[e];
                float lr1 = fmaxf(sv1, ALPHA * sv1);
                float pv1 = ((byq >> (4 + e)) & 1u) ? __expf(lr1) : 0.f;
                l_acc += pv1;
                afr[kc][4 + e] = (short)((__builtin_bit_cast(unsigned, pv1) + 0x8000u) >> 16);
            }
        }
        const short* bb = WhT + (size_t)((j0 + jb) >> 5) * 4096 + q * 8;
        #pragma unroll
        for (int kc = 0; kc < 4; ++kc) {
            const short* bkc = bb + (size_t)kc * 4096;
            #pragma unroll
            for (int nt = 0; nt < 8; ++nt) {
                s16x8 bfr = *(const s16x8*)(bkc + (nt * 16 + m) * 32);
                acc[nt] = __builtin_amdgcn_mfma_f32_16x16x32_bf16(afr[kc], bfr, acc[nt], 0, 0, 0);
            }
        }
    }

    // row-sum over the 4 q-slices
    l_acc += __shfl_xor(l_acc, 16);
    l_acc += __shfl_xor(l_acc, 32);
    if (q == 0) l_part[(size_t)sp * N + row] = l_acc;

    // partials: out row = i0 + w*16 + q*4 + reg, col = nt*16 + m
    float* ap = acc_part + (size_t)sp * N * OUT_F
              + ((size_t)i0 + w * 16 + q * 4) * OUT_F + m;
    #pragma unroll
    for (int reg = 0; reg < 4; ++reg)
        #pragma unroll
        for (int nt = 0; nt < 8; ++nt)
            ap[(size_t)reg * OUT_F + nt * 16] = acc[nt][reg];
}

// ---------------------------------------------------------------------------
// Kernel 3: reduce partials, softmax-divide, elu, classifier.
// ---------------------------------------------------------------------------
__global__ __launch_bounds__(256, 4)
void reduce_kernel(const float* __restrict__ acc_part, const float* __restrict__ l_part,
                   const float* __restrict__ Wc, const float* __restrict__ bcv,
                   float* __restrict__ out) {
    __shared__ __align__(16) float hu[16][OUT_F + 4];
    const int t = threadIdx.x;
    const int i0 = blockIdx.x * 16;
    const int row = t >> 4, cg = t & 15;

    f32x4 v0 = {0.f, 0.f, 0.f, 0.f}, v1 = {0.f, 0.f, 0.f, 0.f};
    float l = 0.f;
    for (int s = 0; s < NSP; ++s) {
        const float* ap = acc_part + (size_t)s * N * OUT_F + (size_t)(i0 + row) * OUT_F + cg * 8;
        v0 += *(const f32x4*)ap;
        v1 += *(const f32x4*)(ap + 4);
        l += l_part[(size_t)s * N + i0 + row];
    }
    float inv = 1.f / l;
    #pragma unroll
    for (int e = 0; e < 4; ++e) {
        float x0 = v0[e] * inv; x0 = x0 > 0.f ? x0 : (__expf(x0) - 1.f);
        float x1 = v1[e] * inv; x1 = x1 > 0.f ? x1 : (__expf(x1) - 1.f);
        hu[row][cg * 8 + e] = x0;
        hu[row][cg * 8 + 4 + e] = x1;
    }
    __syncthreads();

    if (t < 16 * NCLS) {
        int rr = t / NCLS, cls = t - rr * NCLS;
        const f32x4* hurow = (const f32x4*)&hu[rr][0];
        const f32x4* wcrow = (const f32x4*)(Wc + cls * OUT_F);
        float sum = bcv[cls];
        #pragma unroll 8
        for (int c4 = 0; c4 < OUT_F / 4; ++c4) {
            f32x4 hv = hurow[c4];
            f32x4 wv = wcrow[c4];
            sum += hv[0] * wv[0] + hv[1] * wv[1] + hv[2] * wv[2] + hv[3] * wv[3];
        }
        out[(size_t)(i0 + rr) * NCLS + cls] = sum;
    }
}

// ---------------------------------------------------------------------------
extern "C" void kernel_launch(void* const* d_in, const int* in_sizes, int n_in,
                              void* d_out, int out_size, void* d_ws, size_t ws_size,
                              hipStream_t stream) {
    const float* h    = (const float*)d_in[0];
    const int*   dist = (const int*)d_in[1];
    const float* W    = (const float*)d_in[2];
    const float* a    = (const float*)d_in[3];
    const float* Wc   = (const float*)d_in[4];
    const float* bc   = (const float*)d_in[5];
    float* out = (float*)d_out;

    char* ws = (char*)d_ws;
    size_t off = 0;
    short* WhT  = (short*)(ws + off); off += (size_t)OUT_F * N * 2;     // 2 MB
    short* WThi = (short*)(ws + off); off += (size_t)IN_F * OUT_F * 2;  // 128 KB
    short* WTlo = (short*)(ws + off); off += (size_t)IN_F * OUT_F * 2;  // 128 KB
    float* Wh1  = (float*)(ws + off); off += (size_t)N * 4;
    float* Wh2  = (float*)(ws + off); off += (size_t)N * 4;
    float* acc_part = (float*)(ws + off); off += (size_t)NSP * N * OUT_F * 4;  // 32 MB
    float* l_part   = (float*)(ws + off);                                       // 256 KB
    // total ~35 MB; harness ws is ~1 GiB

    hipLaunchKernelGGL(split_w_kernel, dim3(256), dim3(256), 0, stream, W, WThi, WTlo);
    hipLaunchKernelGGL(wh_kernel, dim3(N / WH_ROWS), dim3(256), 0, stream,
                       h, WThi, WTlo, a, WhT, Wh1, Wh2);
    hipLaunchKernelGGL(attn_kernel, dim3(128 * NSP), dim3(256), 0, stream,
                       dist, WhT, Wh1, Wh2, acc_part, l_part);
    hipLaunchKernelGGL(reduce_kernel, dim3(N / 16), dim3(256), 0, stream,
                       acc_part, l_part, Wc, bc, out);
}